// Round 1
// baseline (3119.004 us; speedup 1.0000x reference)
//
#include <hip/hip_runtime.h>
#include <hip/hip_bf16.h>

#define N_NODES 50000
#define N_EDGES 1200000
#define EPS_BN 1e-5f

__global__ void deg_count(const int* __restrict__ row, int* __restrict__ deg, int E){
  int e = blockIdx.x*256 + threadIdx.x;
  if (e < E) atomicAdd(&deg[row[e]], 1);
}

__global__ void make_dinv(const int* __restrict__ deg, float* __restrict__ dinv, int n){
  int i = blockIdx.x*256 + threadIdx.x;
  if (i < n){ int d = deg[i]; dinv[i] = (d>0) ? rsqrtf((float)d) : 0.f; }
}

__global__ void scan_block(const int* __restrict__ deg, int* __restrict__ offs,
                           int* __restrict__ bsums, int n){
  __shared__ int tmp[1024];
  int i = blockIdx.x*1024 + threadIdx.x;
  int v = (i<n) ? deg[i] : 0;
  tmp[threadIdx.x] = v;
  __syncthreads();
  for (int off=1; off<1024; off<<=1){
    int t = (threadIdx.x >= off) ? tmp[threadIdx.x-off] : 0;
    __syncthreads();
    tmp[threadIdx.x] += t;
    __syncthreads();
  }
  if (i<n) offs[i] = tmp[threadIdx.x] - v;           // exclusive within block
  if (threadIdx.x == 1023) bsums[blockIdx.x] = tmp[1023];
}

__global__ void scan_bsums(int* bsums, int nb){
  if (threadIdx.x==0 && blockIdx.x==0){
    int acc=0;
    for (int b=0;b<nb;b++){ int t=bsums[b]; bsums[b]=acc; acc+=t; }
  }
}

__global__ void scan_fix(int* __restrict__ offs, int* __restrict__ cur,
                         const int* __restrict__ bsums, int n, int E){
  int i = blockIdx.x*1024 + threadIdx.x;
  if (i<n){
    int o = offs[i] + bsums[blockIdx.x];
    offs[i] = o; cur[i] = o;
  }
  if (i==0) offs[n] = E;
}

__global__ void csr_fill(const int* __restrict__ row, const int* __restrict__ col,
                         const float* __restrict__ dinv, int* __restrict__ cur,
                         int* __restrict__ ccol, float* __restrict__ cw, int E){
  int e = blockIdx.x*256 + threadIdx.x;
  if (e>=E) return;
  int r = row[e], c = col[e];
  int pos = atomicAdd(&cur[r], 1);
  ccol[pos] = c;
  cw[pos] = -dinv[r]*dinv[c];
}

// dst[row,:] = (sub ? 2*sum - sub[row,:] : sum) where sum = Lhat gather
template<int F>
__global__ void spmm(const int* __restrict__ offs, const int* __restrict__ ccol,
                     const float* __restrict__ cw, const float* __restrict__ src,
                     float* __restrict__ dst, const float* __restrict__ sub, int n){
  int wid = threadIdx.x >> 6;
  int row = blockIdx.x*4 + wid;
  if (row >= n) return;
  int lane = threadIdx.x & 63;
  int s = offs[row], e = offs[row+1];
  float acc[F/64];
  #pragma unroll
  for (int c=0;c<F/64;c++) acc[c]=0.f;
  for (int j=s;j<e;j++){
    int ci = ccol[j];
    float wj = cw[j];
    const float* sp = src + (size_t)ci*F + lane;
    #pragma unroll
    for (int c=0;c<F/64;c++) acc[c] = fmaf(wj, sp[c*64], acc[c]);
  }
  float* dp = dst + (size_t)row*F + lane;
  if (sub){
    const float* sb = sub + (size_t)row*F + lane;
    #pragma unroll
    for (int c=0;c<F/64;c++) dp[c*64] = 2.f*acc[c] - sb[c*64];
  } else {
    #pragma unroll
    for (int c=0;c<F/64;c++) dp[c*64] = acc[c];
  }
}

// out = relu([A0|A1|A2] @ W + bias); stats[0:64]+=col sums, stats[64:128]+=col sumsq
template<int FIN>
__global__ void gemm_fused(const float* __restrict__ A0, const float* __restrict__ A1,
                           const float* __restrict__ A2, const float* __restrict__ W,
                           const float* __restrict__ bias, float* __restrict__ out,
                           float* __restrict__ stats, int n){
  __shared__ float As[32][65];
  __shared__ float Bs[32][65];
  __shared__ float ssum[64], ssq[64];
  int block_row = blockIdx.x * 64;
  int tx = threadIdx.x & 15;
  int ty = threadIdx.x >> 4;
  float acc[4][4] = {{0.f}};
  const float* segs[3] = {A0, A1, A2};
  for (int s=0; s<3; ++s){
    const float* A = segs[s];
    for (int kb=0; kb<FIN; kb+=32){
      for (int t=threadIdx.x; t<64*32; t+=256){
        int m = t >> 5, k = t & 31;
        int gr = block_row + m;
        As[k][m] = (gr<n) ? A[(size_t)gr*FIN + kb + k] : 0.f;
      }
      for (int t=threadIdx.x; t<32*64; t+=256){
        int k = t >> 6, f = t & 63;
        Bs[k][f] = W[(size_t)(s*FIN + kb + k)*64 + f];
      }
      __syncthreads();
      #pragma unroll
      for (int k=0;k<32;k++){
        float a[4], b[4];
        #pragma unroll
        for (int i=0;i<4;i++) a[i] = As[k][ty*4+i];
        #pragma unroll
        for (int j=0;j<4;j++) b[j] = Bs[k][tx*4+j];
        #pragma unroll
        for (int i=0;i<4;i++)
          #pragma unroll
          for (int j=0;j<4;j++) acc[i][j] = fmaf(a[i], b[j], acc[i][j]);
      }
      __syncthreads();
    }
  }
  if (threadIdx.x < 64){ ssum[threadIdx.x]=0.f; ssq[threadIdx.x]=0.f; }
  __syncthreads();
  float csum[4]={0,0,0,0}, csq[4]={0,0,0,0};
  #pragma unroll
  for (int i=0;i<4;i++){
    int r = block_row + ty*4 + i;
    if (r >= n) continue;
    #pragma unroll
    for (int j=0;j<4;j++){
      int f = tx*4 + j;
      float v = acc[i][j] + bias[f];
      v = fmaxf(v, 0.f);
      out[(size_t)r*64 + f] = v;
      csum[j]+=v; csq[j]+=v*v;
    }
  }
  #pragma unroll
  for (int j=0;j<4;j++){
    atomicAdd(&ssum[tx*4+j], csum[j]);
    atomicAdd(&ssq[tx*4+j], csq[j]);
  }
  __syncthreads();
  if (threadIdx.x < 64){
    atomicAdd(&stats[threadIdx.x], ssum[threadIdx.x]);
    atomicAdd(&stats[64+threadIdx.x], ssq[threadIdx.x]);
  }
}

__global__ void bn_apply(float* __restrict__ h, const float* __restrict__ stats,
                         const float* __restrict__ gamma, const float* __restrict__ beta,
                         int n){
  int idx = blockIdx.x*256 + threadIdx.x;
  if (idx >= n*64) return;
  int f = idx & 63;
  float inv_n = 1.0f / (float)n;
  float mu = stats[f] * inv_n;
  float var = stats[64+f] * inv_n - mu*mu;
  float v = h[idx];
  h[idx] = gamma[f]*(v-mu)*rsqrtf(var + EPS_BN) + beta[f];
}

__global__ void final_linear(const float* __restrict__ h, const float* __restrict__ w,
                             const float* __restrict__ b, float* __restrict__ out, int n){
  int i = blockIdx.x*256 + threadIdx.x;
  if (i >= n) return;
  float a0 = b[0], a1 = b[1];
  const float* hp = h + (size_t)i*64;
  #pragma unroll
  for (int k=0;k<64;k++){
    float v = hp[k];
    a0 = fmaf(v, w[k*2+0], a0);
    a1 = fmaf(v, w[k*2+1], a1);
  }
  out[i*2+0] = a0;
  out[i*2+1] = a1;
}

extern "C" void kernel_launch(void* const* d_in, const int* in_sizes, int n_in,
                              void* d_out, int out_size, void* d_ws, size_t ws_size,
                              hipStream_t stream){
  const float* x     = (const float*)d_in[0];
  const int*   ei    = (const int*)d_in[1];
  const float* W1    = (const float*)d_in[2];
  const float* b1    = (const float*)d_in[3];
  const float* Wr    = (const float*)d_in[4];
  const float* br    = (const float*)d_in[5];
  const float* gamma = (const float*)d_in[6];
  const float* beta  = (const float*)d_in[7];
  const float* lw    = (const float*)d_in[8];
  const float* lb    = (const float*)d_in[9];
  const int N = N_NODES, E = N_EDGES;
  const int* row = ei;
  const int* col = ei + E;

  char* ws = (char*)d_ws;
  size_t off = 0;
  auto alloc = [&](size_t bytes)->void*{
    void* p = ws + off; off = (off + bytes + 255) & ~(size_t)255; return p; };
  int*   deg   = (int*)  alloc((size_t)N*4);
  float* dinv  = (float*)alloc((size_t)N*4);
  int*   offs  = (int*)  alloc((size_t)(N+1)*4);
  int*   cur   = (int*)  alloc((size_t)N*4);
  int*   bsums = (int*)  alloc(64*4);
  int*   ccol  = (int*)  alloc((size_t)E*4);
  float* cwv   = (float*)alloc((size_t)E*4);
  float* Tx1   = (float*)alloc((size_t)N*128*4);
  float* Tx2   = (float*)alloc((size_t)N*128*4);
  float* H0    = (float*)alloc((size_t)N*64*4);
  float* H1    = (float*)alloc((size_t)N*64*4);
  float* stats = (float*)alloc(128*4);

  hipMemsetAsync(deg, 0, (size_t)N*4, stream);
  deg_count<<<(E+255)/256, 256, 0, stream>>>(row, deg, E);
  make_dinv<<<(N+255)/256, 256, 0, stream>>>(deg, dinv, N);
  int nb = (N+1023)/1024;
  scan_block<<<nb, 1024, 0, stream>>>(deg, offs, bsums, N);
  scan_bsums<<<1, 64, 0, stream>>>(bsums, nb);
  scan_fix<<<nb, 1024, 0, stream>>>(offs, cur, bsums, N, E);
  csr_fill<<<(E+255)/256, 256, 0, stream>>>(row, col, dinv, cur, ccol, cwv, E);

  // Layer 1 (input width 128)
  spmm<128><<<(N+3)/4, 256, 0, stream>>>(offs, ccol, cwv, x, Tx1, nullptr, N);
  spmm<128><<<(N+3)/4, 256, 0, stream>>>(offs, ccol, cwv, Tx1, Tx2, x, N);
  hipMemsetAsync(stats, 0, 128*4, stream);
  gemm_fused<128><<<(N+63)/64, 256, 0, stream>>>(x, Tx1, Tx2, W1, b1, H0, stats, N);
  bn_apply<<<((size_t)N*64+255)/256, 256, 0, stream>>>(H0, stats, gamma, beta, N);

  // Layers 2..10 (width 64)
  float* hin = H0; float* hout = H1;
  for (int L=0; L<9; ++L){
    spmm<64><<<(N+3)/4, 256, 0, stream>>>(offs, ccol, cwv, hin, Tx1, nullptr, N);
    spmm<64><<<(N+3)/4, 256, 0, stream>>>(offs, ccol, cwv, Tx1, Tx2, hin, N);
    hipMemsetAsync(stats, 0, 128*4, stream);
    gemm_fused<64><<<(N+63)/64, 256, 0, stream>>>(hin, Tx1, Tx2,
        Wr + (size_t)L*3*64*64, br + (size_t)L*64, hout, stats, N);
    bn_apply<<<((size_t)N*64+255)/256, 256, 0, stream>>>(hout, stats,
        gamma + (size_t)(L+1)*64, beta + (size_t)(L+1)*64, N);
    float* t = hin; hin = hout; hout = t;
  }

  final_linear<<<(N+255)/256, 256, 0, stream>>>(hin, lw, lb, (float*)d_out, N);
}

// Round 4
// 1612.530 us; speedup vs baseline: 1.9342x; 1.9342x over previous
//
#include <hip/hip_runtime.h>
#include <hip/hip_bf16.h>

#define N_NODES 50000
#define N_EDGES 1200000
#define EPS_BN 1e-5f

typedef __attribute__((ext_vector_type(8))) short short8;
typedef __attribute__((ext_vector_type(4))) float f32x4;

union U16x8 { uint4 u; short8 s; };

__device__ __forceinline__ float lo2f(unsigned int u){ return __uint_as_float(u << 16); }
__device__ __forceinline__ float hi2f(unsigned int u){ return __uint_as_float(u & 0xffff0000u); }
__device__ __forceinline__ float b2f(unsigned short u){ return __uint_as_float(((unsigned int)u) << 16); }
__device__ __forceinline__ unsigned short f2b(float f){
  __hip_bfloat16 b = __float2bfloat16(f);
  return __builtin_bit_cast(unsigned short, b);
}

// ---------------- CSR build ----------------
__global__ void deg_count(const int* __restrict__ row, int* __restrict__ deg, int E){
  int e = blockIdx.x*256 + threadIdx.x;
  if (e < E) atomicAdd(&deg[row[e]], 1);
}

__global__ void make_dinv(const int* __restrict__ deg, float* __restrict__ dinv, int n){
  int i = blockIdx.x*256 + threadIdx.x;
  if (i < n){ int d = deg[i]; dinv[i] = (d>0) ? rsqrtf((float)d) : 0.f; }
}

__global__ void scan_block(const int* __restrict__ deg, int* __restrict__ offs,
                           int* __restrict__ bsums, int n){
  __shared__ int tmp[1024];
  int i = blockIdx.x*1024 + threadIdx.x;
  int v = (i<n) ? deg[i] : 0;
  tmp[threadIdx.x] = v;
  __syncthreads();
  for (int off=1; off<1024; off<<=1){
    int t = (threadIdx.x >= off) ? tmp[threadIdx.x-off] : 0;
    __syncthreads();
    tmp[threadIdx.x] += t;
    __syncthreads();
  }
  if (i<n) offs[i] = tmp[threadIdx.x] - v;
  if (threadIdx.x == 1023) bsums[blockIdx.x] = tmp[1023];
}

__global__ void scan_bsums(int* bsums, int nb){
  if (threadIdx.x==0 && blockIdx.x==0){
    int acc=0;
    for (int b=0;b<nb;b++){ int t=bsums[b]; bsums[b]=acc; acc+=t; }
  }
}

__global__ void scan_fix(int* __restrict__ offs, int* __restrict__ cur,
                         const int* __restrict__ bsums, int n, int E){
  int i = blockIdx.x*1024 + threadIdx.x;
  if (i<n){
    int o = offs[i] + bsums[blockIdx.x];
    offs[i] = o; cur[i] = o;
  }
  if (i==0) offs[n] = E;
}

__global__ void csr_fill(const int* __restrict__ row, const int* __restrict__ col,
                         const float* __restrict__ dinv, int* __restrict__ cur,
                         int2* __restrict__ ep, int E){
  int e = blockIdx.x*256 + threadIdx.x;
  if (e>=E) return;
  int r = row[e], c = col[e];
  int pos = atomicAdd(&cur[r], 1);
  float w = -dinv[r]*dinv[c];
  ep[pos] = make_int2(c, __float_as_int(w));
}

// ---------------- prep: x -> bf16 hi/lo planes ----------------
__global__ void cast_x_split(const float4* __restrict__ x, ushort4* __restrict__ xh,
                             ushort4* __restrict__ xl, int n4){
  int t = blockIdx.x*256 + threadIdx.x;
  if (t >= n4) return;
  float4 v = x[t];
  ushort4 h, l;
  h.x = f2b(v.x); l.x = f2b(v.x - b2f(h.x));
  h.y = f2b(v.y); l.y = f2b(v.y - b2f(h.y));
  h.z = f2b(v.z); l.z = f2b(v.z - b2f(h.z));
  h.w = f2b(v.w); l.w = f2b(v.w - b2f(h.w));
  xh[t] = h; xl[t] = l;
}

// ---- weights: fold (W0-W2, W1, 2*W2), transpose to [64][K], split hi/lo ----
__global__ void transpose_w_split(const float* __restrict__ W1, const float* __restrict__ Wr,
                                  unsigned short* __restrict__ WTh,
                                  unsigned short* __restrict__ WTl){
  int t = blockIdx.x*256 + threadIdx.x;
  float val;
  if (t < 24576){
    int c = t/384, kk = t%384;
    int seg = kk/128, f = kk%128;
    if (seg==0)      val = W1[(size_t)f*64 + c] - W1[(size_t)(256+f)*64 + c];
    else if (seg==1) val = W1[(size_t)(128+f)*64 + c];
    else             val = 2.f * W1[(size_t)(256+f)*64 + c];
  } else if (t < 135168){
    int u = t - 24576;
    int L = u/12288, r2 = u%12288;
    int c = r2/192, kk = r2%192;
    int seg = kk/64, f = kk%64;
    const float* WL = Wr + (size_t)L*12288;
    if (seg==0)      val = WL[(size_t)f*64 + c] - WL[(size_t)(128+f)*64 + c];
    else if (seg==1) val = WL[(size_t)(64+f)*64 + c];
    else             val = 2.f * WL[(size_t)(128+f)*64 + c];
  } else return;
  unsigned short h = f2b(val);
  WTh[t] = h;
  WTl[t] = f2b(val - b2f(h));
}

// ---------------- SpMM: dst = Lhat @ src ----------------
template<int F>
__global__ void spmm_bf16(const int* __restrict__ offs, const int2* __restrict__ ep,
                          const unsigned short* __restrict__ src,
                          unsigned short* __restrict__ dst, int n){
  constexpr int LPR = F/4;
  constexpr int RPW = 64/LPR;
  int lane = threadIdx.x & 63;
  int wv = threadIdx.x >> 6;
  int lr = lane / LPR;
  int li = lane % LPR;
  int row = (blockIdx.x*4 + wv)*RPW + lr;
  int s = 0, e = 0;
  if (row < n){ s = offs[row]; e = offs[row+1]; }
  float a0=0.f, a1=0.f, a2=0.f, a3=0.f;
  const int fb = li*4;
  for (int j=s; j<e; ++j){
    int2 eg = ep[j];
    float w = __int_as_float(eg.y);
    uint2 u = *(const uint2*)(src + (size_t)eg.x*F + fb);
    a0 = fmaf(w, lo2f(u.x), a0);
    a1 = fmaf(w, hi2f(u.x), a1);
    a2 = fmaf(w, lo2f(u.y), a2);
    a3 = fmaf(w, hi2f(u.y), a3);
  }
  if (row < n){
    ushort4 o;
    o.x = f2b(a0); o.y = f2b(a1); o.z = f2b(a2); o.w = f2b(a3);
    *(ushort4*)(dst + (size_t)row*F + fb) = o;
  }
}

// ---- MFMA GEMM with folded weights; A0 hi/lo, A1/A2 single bf16, W hi/lo ----
template<int SEGF>
__global__ void gemm_mfma(const unsigned short* __restrict__ A0h,
                          const unsigned short* __restrict__ A0l,
                          const unsigned short* __restrict__ A1,
                          const unsigned short* __restrict__ A2,
                          const unsigned short* __restrict__ WTh,   // [64][K]
                          const unsigned short* __restrict__ WTl,
                          const float* __restrict__ bias,
                          float* __restrict__ out,
                          float* __restrict__ stats, int n){
  constexpr int K = 3*SEGF;
  constexpr int KSTEPS = K/32;
  constexpr int KPS = SEGF/32;
  __shared__ float ssum[64];
  __shared__ float ssq[64];
  if (threadIdx.x < 64){ ssum[threadIdx.x] = 0.f; ssq[threadIdx.x] = 0.f; }
  __syncthreads();

  int lane = threadIdx.x & 63;
  int wv = threadIdx.x >> 6;
  int mrow = lane & 15;
  int kg = lane >> 4;
  int brow = blockIdx.x*64 + wv*16;
  int m = brow + mrow;
  bool mv = m < n;

  f32x4 acc[4];
  #pragma unroll
  for (int t=0;t<4;t++) acc[t] = f32x4{0.f,0.f,0.f,0.f};

  #pragma unroll
  for (int ks=0; ks<KSTEPS; ++ks){
    const int seg = ks/KPS;
    const unsigned short* Ah = (seg==0) ? A0h : (seg==1) ? A1 : A2;
    int koff = (ks%KPS)*32 + kg*8;
    U16x8 a_hi, a_lo;
    if (mv) a_hi.u = *(const uint4*)(Ah + (size_t)m*SEGF + koff);
    else    a_hi.u = make_uint4(0,0,0,0);
    if (seg==0){
      if (mv) a_lo.u = *(const uint4*)(A0l + (size_t)m*SEGF + koff);
      else    a_lo.u = make_uint4(0,0,0,0);
    }
    int kb = ks*32 + kg*8;
    #pragma unroll
    for (int t=0;t<4;t++){
      int col = t*16 + mrow;
      U16x8 bh, bl;
      bh.u = *(const uint4*)(WTh + (size_t)col*K + kb);
      bl.u = *(const uint4*)(WTl + (size_t)col*K + kb);
      acc[t] = __builtin_amdgcn_mfma_f32_16x16x32_bf16(a_hi.s, bh.s, acc[t], 0, 0, 0);
      acc[t] = __builtin_amdgcn_mfma_f32_16x16x32_bf16(a_hi.s, bl.s, acc[t], 0, 0, 0);
      if (seg==0)
        acc[t] = __builtin_amdgcn_mfma_f32_16x16x32_bf16(a_lo.s, bh.s, acc[t], 0, 0, 0);
    }
  }

  #pragma unroll
  for (int t=0;t<4;t++){
    int col = t*16 + mrow;
    float bsv = bias[col];
    float s = 0.f, sq = 0.f;
    #pragma unroll
    for (int i=0;i<4;i++){
      int r = brow + kg*4 + i;
      float v = fmaxf(acc[t][i] + bsv, 0.f);
      if (r < n){
        out[(size_t)r*64 + col] = v;
        s += v; sq += v*v;
      }
    }
    s  += __shfl_xor(s, 16);  sq += __shfl_xor(sq, 16);
    s  += __shfl_xor(s, 32);  sq += __shfl_xor(sq, 32);
    if (kg == 0){
      atomicAdd(&ssum[col], s);
      atomicAdd(&ssq[col], sq);
    }
  }
  __syncthreads();
  if (threadIdx.x < 64){
    atomicAdd(&stats[threadIdx.x], ssum[threadIdx.x]);
    atomicAdd(&stats[64+threadIdx.x], ssq[threadIdx.x]);
  }
}

// ---------------- BN: fp32 in, bf16 hi/lo out ----------------
__global__ void bn_f32_split(const float* __restrict__ g_in,
                             unsigned short* __restrict__ hh, unsigned short* __restrict__ hl,
                             const float* __restrict__ stats,
                             const float* __restrict__ gamma, const float* __restrict__ beta,
                             int n){
  int t = blockIdx.x*256 + threadIdx.x;
  if (t >= n*8) return;
  int fb = (t & 7)*8;
  int node = t >> 3;
  float inv_n = 1.f/(float)n;
  const float* gp = g_in + (size_t)node*64 + fb;
  float4 v0 = *(const float4*)gp;
  float4 v1 = *(const float4*)(gp + 4);
  float vv[8] = {v0.x, v0.y, v0.z, v0.w, v1.x, v1.y, v1.z, v1.w};
  unsigned int oh[4], ol[4];
  #pragma unroll
  for (int p=0;p<4;p++){
    int f0 = fb + 2*p, f1 = f0 + 1;
    float mu0 = stats[f0]*inv_n, mu1 = stats[f1]*inv_n;
    float va0 = stats[64+f0]*inv_n - mu0*mu0;
    float va1 = stats[64+f1]*inv_n - mu1*mu1;
    float a0 = gamma[f0]*rsqrtf(va0+EPS_BN);
    float a1 = gamma[f1]*rsqrtf(va1+EPS_BN);
    float c0 = beta[f0] - mu0*a0;
    float c1 = beta[f1] - mu1*a1;
    float y0 = fmaf(vv[2*p],   a0, c0);
    float y1 = fmaf(vv[2*p+1], a1, c1);
    unsigned short h0 = f2b(y0), h1 = f2b(y1);
    unsigned short l0 = f2b(y0 - b2f(h0)), l1 = f2b(y1 - b2f(h1));
    oh[p] = (unsigned int)h0 | ((unsigned int)h1 << 16);
    ol[p] = (unsigned int)l0 | ((unsigned int)l1 << 16);
  }
  ((uint4*)hh)[t] = make_uint4(oh[0], oh[1], oh[2], oh[3]);
  ((uint4*)hl)[t] = make_uint4(ol[0], ol[1], ol[2], ol[3]);
}

// ---------------- final linear 64 -> 2 ----------------
__global__ void final_linear_split(const unsigned short* __restrict__ hh,
                                   const unsigned short* __restrict__ hl,
                                   const float* __restrict__ w, const float* __restrict__ b,
                                   float* __restrict__ out, int n){
  int i = blockIdx.x*256 + threadIdx.x;
  if (i >= n) return;
  float a0 = b[0], a1 = b[1];
  const unsigned int* hp = (const unsigned int*)(hh + (size_t)i*64);
  const unsigned int* lp = (const unsigned int*)(hl + (size_t)i*64);
  #pragma unroll
  for (int k=0;k<32;k++){
    unsigned int uh = hp[k], ul = lp[k];
    float v0 = lo2f(uh) + lo2f(ul);
    float v1 = hi2f(uh) + hi2f(ul);
    a0 = fmaf(v0, w[(2*k)*2+0], a0);
    a1 = fmaf(v0, w[(2*k)*2+1], a1);
    a0 = fmaf(v1, w[(2*k+1)*2+0], a0);
    a1 = fmaf(v1, w[(2*k+1)*2+1], a1);
  }
  out[i*2+0] = a0;
  out[i*2+1] = a1;
}

extern "C" void kernel_launch(void* const* d_in, const int* in_sizes, int n_in,
                              void* d_out, int out_size, void* d_ws, size_t ws_size,
                              hipStream_t stream){
  const float* x     = (const float*)d_in[0];
  const int*   ei    = (const int*)d_in[1];
  const float* W1    = (const float*)d_in[2];
  const float* b1    = (const float*)d_in[3];
  const float* Wr    = (const float*)d_in[4];
  const float* br    = (const float*)d_in[5];
  const float* gamma = (const float*)d_in[6];
  const float* beta  = (const float*)d_in[7];
  const float* lw    = (const float*)d_in[8];
  const float* lb    = (const float*)d_in[9];
  const int N = N_NODES, E = N_EDGES;
  const int* row = ei;
  const int* col = ei + E;

  char* ws = (char*)d_ws;
  size_t off = 0;
  auto alloc = [&](size_t bytes)->void*{
    void* p = ws + off; off = (off + bytes + 255) & ~(size_t)255; return p; };
  int*            deg   = (int*)   alloc((size_t)N*4);
  float*          dinv  = (float*) alloc((size_t)N*4);
  int*            offs  = (int*)   alloc((size_t)(N+1)*4);
  int*            cur   = (int*)   alloc((size_t)N*4);
  int*            bsums = (int*)   alloc(64*4);
  int2*           ep    = (int2*)  alloc((size_t)E*8);
  unsigned short* xbh   = (unsigned short*)alloc((size_t)N*128*2);
  unsigned short* xbl   = (unsigned short*)alloc((size_t)N*128*2);
  unsigned short* T1    = (unsigned short*)alloc((size_t)N*128*2);
  unsigned short* Ub    = (unsigned short*)alloc((size_t)N*128*2);
  unsigned short* H0h   = (unsigned short*)alloc((size_t)N*64*2);
  unsigned short* H0l   = (unsigned short*)alloc((size_t)N*64*2);
  unsigned short* H1h   = (unsigned short*)alloc((size_t)N*64*2);
  unsigned short* H1l   = (unsigned short*)alloc((size_t)N*64*2);
  float*          gbuf  = (float*) alloc((size_t)N*64*4);
  unsigned short* WTh   = (unsigned short*)alloc((size_t)135168*2);
  unsigned short* WTl   = (unsigned short*)alloc((size_t)135168*2);
  float*          stats = (float*) alloc((size_t)1280*4);

  hipMemsetAsync(deg, 0, (size_t)N*4, stream);
  hipMemsetAsync(stats, 0, (size_t)1280*4, stream);
  deg_count<<<(E+255)/256, 256, 0, stream>>>(row, deg, E);
  make_dinv<<<(N+255)/256, 256, 0, stream>>>(deg, dinv, N);
  int nb = (N+1023)/1024;
  scan_block<<<nb, 1024, 0, stream>>>(deg, offs, bsums, N);
  scan_bsums<<<1, 64, 0, stream>>>(bsums, nb);
  scan_fix<<<nb, 1024, 0, stream>>>(offs, cur, bsums, N, E);
  csr_fill<<<(E+255)/256, 256, 0, stream>>>(row, col, dinv, cur, ep, E);

  cast_x_split<<<((N*32)+255)/256, 256, 0, stream>>>((const float4*)x,
      (ushort4*)xbh, (ushort4*)xbl, N*32);
  transpose_w_split<<<(135168+255)/256, 256, 0, stream>>>(W1, Wr, WTh, WTl);

  // ---- layer 1 (SEGF=128) ----
  spmm_bf16<128><<<(N+7)/8, 256, 0, stream>>>(offs, ep, xbh, T1, N);
  spmm_bf16<128><<<(N+7)/8, 256, 0, stream>>>(offs, ep, T1, Ub, N);
  gemm_mfma<128><<<(N+63)/64, 256, 0, stream>>>(xbh, xbl, T1, Ub, WTh, WTl,
      b1, gbuf, stats, N);
  bn_f32_split<<<((N*8)+255)/256, 256, 0, stream>>>(gbuf, H0h, H0l, stats, gamma, beta, N);

  // ---- layers 2..10 (SEGF=64) ----
  unsigned short *hinh = H0h, *hinl = H0l, *houth = H1h, *houtl = H1l;
  for (int L=0; L<9; ++L){
    spmm_bf16<64><<<(N+15)/16, 256, 0, stream>>>(offs, ep, hinh, T1, N);
    spmm_bf16<64><<<(N+15)/16, 256, 0, stream>>>(offs, ep, T1, Ub, N);
    gemm_mfma<64><<<(N+63)/64, 256, 0, stream>>>(hinh, hinl, T1, Ub,
        WTh + 24576 + (size_t)L*12288, WTl + 24576 + (size_t)L*12288,
        br + (size_t)L*64, gbuf, stats + (size_t)(L+1)*128, N);
    bn_f32_split<<<((N*8)+255)/256, 256, 0, stream>>>(gbuf, houth, houtl,
        stats + (size_t)(L+1)*128, gamma + (size_t)(L+1)*64, beta + (size_t)(L+1)*64, N);
    unsigned short* t;
    t = hinh; hinh = houth; houth = t;
    t = hinl; hinl = houtl; houtl = t;
  }

  final_linear_split<<<(N+255)/256, 256, 0, stream>>>(hinh, hinl, lw, lb, (float*)d_out, N);
}

// Round 6
// 1142.333 us; speedup vs baseline: 2.7304x; 1.4116x over previous
//
#include <hip/hip_runtime.h>
#include <hip/hip_bf16.h>

#define N_NODES 50000
#define N_EDGES 1200000
#define EPS_BN 1e-5f

typedef __attribute__((ext_vector_type(8))) short short8;
typedef __attribute__((ext_vector_type(4))) float f32x4;

union U16x8 { uint4 u; short8 s; };

__device__ __forceinline__ float lo2f(unsigned int u){ return __uint_as_float(u << 16); }
__device__ __forceinline__ float hi2f(unsigned int u){ return __uint_as_float(u & 0xffff0000u); }
__device__ __forceinline__ float b2f(unsigned short u){ return __uint_as_float(((unsigned int)u) << 16); }
__device__ __forceinline__ unsigned short f2b(float f){
  __hip_bfloat16 b = __float2bfloat16(f);
  return __builtin_bit_cast(unsigned short, b);
}

// ---------------- CSR build ----------------
__global__ void deg_count(const int* __restrict__ row, int* __restrict__ deg, int E){
  int e = blockIdx.x*256 + threadIdx.x;
  if (e < E) atomicAdd(&deg[row[e]], 1);
}

__global__ void make_dinv(const int* __restrict__ deg, float* __restrict__ dinv, int n){
  int i = blockIdx.x*256 + threadIdx.x;
  if (i < n){ int d = deg[i]; dinv[i] = (d>0) ? rsqrtf((float)d) : 0.f; }
}

__global__ void scan_block(const int* __restrict__ deg, int* __restrict__ offs,
                           int* __restrict__ bsums, int n){
  __shared__ int tmp[1024];
  int i = blockIdx.x*1024 + threadIdx.x;
  int v = (i<n) ? deg[i] : 0;
  tmp[threadIdx.x] = v;
  __syncthreads();
  for (int off=1; off<1024; off<<=1){
    int t = (threadIdx.x >= off) ? tmp[threadIdx.x-off] : 0;
    __syncthreads();
    tmp[threadIdx.x] += t;
    __syncthreads();
  }
  if (i<n) offs[i] = tmp[threadIdx.x] - v;
  if (threadIdx.x == 1023) bsums[blockIdx.x] = tmp[1023];
}

__global__ void scan_bsums(int* bsums, int nb){
  if (threadIdx.x==0 && blockIdx.x==0){
    int acc=0;
    for (int b=0;b<nb;b++){ int t=bsums[b]; bsums[b]=acc; acc+=t; }
  }
}

__global__ void scan_fix(int* __restrict__ offs, int* __restrict__ cur,
                         const int* __restrict__ bsums, int n, int E){
  int i = blockIdx.x*1024 + threadIdx.x;
  if (i<n){
    int o = offs[i] + bsums[blockIdx.x];
    offs[i] = o; cur[i] = o;
  }
  if (i==0) offs[n] = E;
}

__global__ void csr_fill(const int* __restrict__ row, const int* __restrict__ col,
                         const float* __restrict__ dinv, int* __restrict__ cur,
                         int2* __restrict__ ep, int E){
  int e = blockIdx.x*256 + threadIdx.x;
  if (e>=E) return;
  int r = row[e], c = col[e];
  int pos = atomicAdd(&cur[r], 1);
  float w = -dinv[r]*dinv[c];
  ep[pos] = make_int2(c, __float_as_int(w));
}

// ---------------- prep: x -> bf16 hi/lo planes ----------------
__global__ void cast_x_split(const float4* __restrict__ x, ushort4* __restrict__ xh,
                             ushort4* __restrict__ xl, int n4){
  int t = blockIdx.x*256 + threadIdx.x;
  if (t >= n4) return;
  float4 v = x[t];
  ushort4 h, l;
  h.x = f2b(v.x); l.x = f2b(v.x - b2f(h.x));
  h.y = f2b(v.y); l.y = f2b(v.y - b2f(h.y));
  h.z = f2b(v.z); l.z = f2b(v.z - b2f(h.z));
  h.w = f2b(v.w); l.w = f2b(v.w - b2f(h.w));
  xh[t] = h; xl[t] = l;
}

// ---- weights: fold (W0-W2, W1, 2*W2), transpose to [64][K], split hi/lo ----
__global__ void transpose_w_split(const float* __restrict__ W1, const float* __restrict__ Wr,
                                  unsigned short* __restrict__ WTh,
                                  unsigned short* __restrict__ WTl){
  int t = blockIdx.x*256 + threadIdx.x;
  float val;
  if (t < 24576){
    int c = t/384, kk = t%384;
    int seg = kk/128, f = kk%128;
    if (seg==0)      val = W1[(size_t)f*64 + c] - W1[(size_t)(256+f)*64 + c];
    else if (seg==1) val = W1[(size_t)(128+f)*64 + c];
    else             val = 2.f * W1[(size_t)(256+f)*64 + c];
  } else if (t < 135168){
    int u = t - 24576;
    int L = u/12288, r2 = u%12288;
    int c = r2/192, kk = r2%192;
    int seg = kk/64, f = kk%64;
    const float* WL = Wr + (size_t)L*12288;
    if (seg==0)      val = WL[(size_t)f*64 + c] - WL[(size_t)(128+f)*64 + c];
    else if (seg==1) val = WL[(size_t)(64+f)*64 + c];
    else             val = 2.f * WL[(size_t)(128+f)*64 + c];
  } else return;
  unsigned short h = f2b(val);
  WTh[t] = h;
  WTl[t] = f2b(val - b2f(h));
}

// ---------------- SpMM: dst = Lhat @ src ----------------
// 16B per lane: F=64 -> 8 lanes/row, 8 rows/wave; F=128 -> 16 lanes/row, 4 rows/wave.
// Edge loop chunked x4: 4 independent gathers in flight per row-group.
__device__ __forceinline__ void spmm_acc8(float wt, uint4 u, float* a){
  a[0] = fmaf(wt, lo2f(u.x), a[0]);
  a[1] = fmaf(wt, hi2f(u.x), a[1]);
  a[2] = fmaf(wt, lo2f(u.y), a[2]);
  a[3] = fmaf(wt, hi2f(u.y), a[3]);
  a[4] = fmaf(wt, lo2f(u.z), a[4]);
  a[5] = fmaf(wt, hi2f(u.z), a[5]);
  a[6] = fmaf(wt, lo2f(u.w), a[6]);
  a[7] = fmaf(wt, hi2f(u.w), a[7]);
}

template<int F>
__global__ void spmm_bf16(const int* __restrict__ offs, const int2* __restrict__ ep,
                          const unsigned short* __restrict__ src,
                          unsigned short* __restrict__ dst, int n){
  constexpr int LPR = F/8;       // lanes per row (8 bf16 = 16B per lane)
  constexpr int RPW = 64/LPR;    // rows per wave
  int lane = threadIdx.x & 63;
  int wv = threadIdx.x >> 6;
  int lr = lane / LPR;
  int li = lane % LPR;
  int row = (blockIdx.x*4 + wv)*RPW + lr;
  int s = 0, e = 0;
  if (row < n){ s = offs[row]; e = offs[row+1]; }
  float a[8];
  #pragma unroll
  for (int c=0;c<8;c++) a[c]=0.f;
  const int fb = li*8;
  int j = s;
  for (; j+4 <= e; j += 4){
    int2 q0 = ep[j+0];
    int2 q1 = ep[j+1];
    int2 q2 = ep[j+2];
    int2 q3 = ep[j+3];
    uint4 u0 = *(const uint4*)(src + (size_t)q0.x*F + fb);
    uint4 u1 = *(const uint4*)(src + (size_t)q1.x*F + fb);
    uint4 u2 = *(const uint4*)(src + (size_t)q2.x*F + fb);
    uint4 u3 = *(const uint4*)(src + (size_t)q3.x*F + fb);
    spmm_acc8(__int_as_float(q0.y), u0, a);
    spmm_acc8(__int_as_float(q1.y), u1, a);
    spmm_acc8(__int_as_float(q2.y), u2, a);
    spmm_acc8(__int_as_float(q3.y), u3, a);
  }
  for (; j < e; ++j){
    int2 q = ep[j];
    uint4 u = *(const uint4*)(src + (size_t)q.x*F + fb);
    spmm_acc8(__int_as_float(q.y), u, a);
  }
  if (row < n){
    uint4 o;
    o.x = (unsigned int)f2b(a[0]) | ((unsigned int)f2b(a[1]) << 16);
    o.y = (unsigned int)f2b(a[2]) | ((unsigned int)f2b(a[3]) << 16);
    o.z = (unsigned int)f2b(a[4]) | ((unsigned int)f2b(a[5]) << 16);
    o.w = (unsigned int)f2b(a[6]) | ((unsigned int)f2b(a[7]) << 16);
    *(uint4*)(dst + (size_t)row*F + fb) = o;
  }
}

// ---- MFMA GEMM with folded weights; A0 hi/lo, A1/A2 single bf16, W hi/lo ----
template<int SEGF>
__global__ void gemm_mfma(const unsigned short* __restrict__ A0h,
                          const unsigned short* __restrict__ A0l,
                          const unsigned short* __restrict__ A1,
                          const unsigned short* __restrict__ A2,
                          const unsigned short* __restrict__ WTh,   // [64][K]
                          const unsigned short* __restrict__ WTl,
                          const float* __restrict__ bias,
                          float* __restrict__ out,
                          float* __restrict__ stats, int n){
  constexpr int K = 3*SEGF;
  constexpr int KSTEPS = K/32;
  constexpr int KPS = SEGF/32;
  __shared__ float ssum[64];
  __shared__ float ssq[64];
  if (threadIdx.x < 64){ ssum[threadIdx.x] = 0.f; ssq[threadIdx.x] = 0.f; }
  __syncthreads();

  int lane = threadIdx.x & 63;
  int wv = threadIdx.x >> 6;
  int mrow = lane & 15;
  int kg = lane >> 4;
  int brow = blockIdx.x*64 + wv*16;
  int m = brow + mrow;
  bool mv = m < n;

  f32x4 acc[4];
  #pragma unroll
  for (int t=0;t<4;t++) acc[t] = f32x4{0.f,0.f,0.f,0.f};

  #pragma unroll
  for (int ks=0; ks<KSTEPS; ++ks){
    const int seg = ks/KPS;
    const unsigned short* Ah = (seg==0) ? A0h : (seg==1) ? A1 : A2;
    int koff = (ks%KPS)*32 + kg*8;
    U16x8 a_hi, a_lo;
    if (mv) a_hi.u = *(const uint4*)(Ah + (size_t)m*SEGF + koff);
    else    a_hi.u = make_uint4(0,0,0,0);
    if (seg==0){
      if (mv) a_lo.u = *(const uint4*)(A0l + (size_t)m*SEGF + koff);
      else    a_lo.u = make_uint4(0,0,0,0);
    }
    int kb = ks*32 + kg*8;
    #pragma unroll
    for (int t=0;t<4;t++){
      int col = t*16 + mrow;
      U16x8 bh, bl;
      bh.u = *(const uint4*)(WTh + (size_t)col*K + kb);
      bl.u = *(const uint4*)(WTl + (size_t)col*K + kb);
      acc[t] = __builtin_amdgcn_mfma_f32_16x16x32_bf16(a_hi.s, bh.s, acc[t], 0, 0, 0);
      acc[t] = __builtin_amdgcn_mfma_f32_16x16x32_bf16(a_hi.s, bl.s, acc[t], 0, 0, 0);
      if (seg==0)
        acc[t] = __builtin_amdgcn_mfma_f32_16x16x32_bf16(a_lo.s, bh.s, acc[t], 0, 0, 0);
    }
  }

  #pragma unroll
  for (int t=0;t<4;t++){
    int col = t*16 + mrow;
    float bsv = bias[col];
    float s = 0.f, sq = 0.f;
    #pragma unroll
    for (int i=0;i<4;i++){
      int r = brow + kg*4 + i;
      float v = fmaxf(acc[t][i] + bsv, 0.f);
      if (r < n){
        out[(size_t)r*64 + col] = v;
        s += v; sq += v*v;
      }
    }
    s  += __shfl_xor(s, 16);  sq += __shfl_xor(sq, 16);
    s  += __shfl_xor(s, 32);  sq += __shfl_xor(sq, 32);
    if (kg == 0){
      atomicAdd(&ssum[col], s);
      atomicAdd(&ssq[col], sq);
    }
  }
  __syncthreads();
  if (threadIdx.x < 64){
    atomicAdd(&stats[threadIdx.x], ssum[threadIdx.x]);
    atomicAdd(&stats[64+threadIdx.x], ssq[threadIdx.x]);
  }
}

// ---------------- BN: fp32 in, bf16 hi/lo out ----------------
__global__ void bn_f32_split(const float* __restrict__ g_in,
                             unsigned short* __restrict__ hh, unsigned short* __restrict__ hl,
                             const float* __restrict__ stats,
                             const float* __restrict__ gamma, const float* __restrict__ beta,
                             int n){
  int t = blockIdx.x*256 + threadIdx.x;
  if (t >= n*8) return;
  int fb = (t & 7)*8;
  int node = t >> 3;
  float inv_n = 1.f/(float)n;
  const float* gp = g_in + (size_t)node*64 + fb;
  float4 v0 = *(const float4*)gp;
  float4 v1 = *(const float4*)(gp + 4);
  float vv[8] = {v0.x, v0.y, v0.z, v0.w, v1.x, v1.y, v1.z, v1.w};
  unsigned int oh[4], ol[4];
  #pragma unroll
  for (int p=0;p<4;p++){
    int f0 = fb + 2*p, f1 = f0 + 1;
    float mu0 = stats[f0]*inv_n, mu1 = stats[f1]*inv_n;
    float va0 = stats[64+f0]*inv_n - mu0*mu0;
    float va1 = stats[64+f1]*inv_n - mu1*mu1;
    float a0 = gamma[f0]*rsqrtf(va0+EPS_BN);
    float a1 = gamma[f1]*rsqrtf(va1+EPS_BN);
    float c0 = beta[f0] - mu0*a0;
    float c1 = beta[f1] - mu1*a1;
    float y0 = fmaf(vv[2*p],   a0, c0);
    float y1 = fmaf(vv[2*p+1], a1, c1);
    unsigned short h0 = f2b(y0), h1 = f2b(y1);
    unsigned short l0 = f2b(y0 - b2f(h0)), l1 = f2b(y1 - b2f(h1));
    oh[p] = (unsigned int)h0 | ((unsigned int)h1 << 16);
    ol[p] = (unsigned int)l0 | ((unsigned int)l1 << 16);
  }
  ((uint4*)hh)[t] = make_uint4(oh[0], oh[1], oh[2], oh[3]);
  ((uint4*)hl)[t] = make_uint4(ol[0], ol[1], ol[2], ol[3]);
}

// ---------------- final linear 64 -> 2 ----------------
__global__ void final_linear_split(const unsigned short* __restrict__ hh,
                                   const unsigned short* __restrict__ hl,
                                   const float* __restrict__ w, const float* __restrict__ b,
                                   float* __restrict__ out, int n){
  int i = blockIdx.x*256 + threadIdx.x;
  if (i >= n) return;
  float a0 = b[0], a1 = b[1];
  const unsigned int* hp = (const unsigned int*)(hh + (size_t)i*64);
  const unsigned int* lp = (const unsigned int*)(hl + (size_t)i*64);
  #pragma unroll
  for (int k=0;k<32;k++){
    unsigned int uh = hp[k], ul = lp[k];
    float v0 = lo2f(uh) + lo2f(ul);
    float v1 = hi2f(uh) + hi2f(ul);
    a0 = fmaf(v0, w[(2*k)*2+0], a0);
    a1 = fmaf(v0, w[(2*k)*2+1], a1);
    a0 = fmaf(v1, w[(2*k+1)*2+0], a0);
    a1 = fmaf(v1, w[(2*k+1)*2+1], a1);
  }
  out[i*2+0] = a0;
  out[i*2+1] = a1;
}

extern "C" void kernel_launch(void* const* d_in, const int* in_sizes, int n_in,
                              void* d_out, int out_size, void* d_ws, size_t ws_size,
                              hipStream_t stream){
  const float* x     = (const float*)d_in[0];
  const int*   ei    = (const int*)d_in[1];
  const float* W1    = (const float*)d_in[2];
  const float* b1    = (const float*)d_in[3];
  const float* Wr    = (const float*)d_in[4];
  const float* br    = (const float*)d_in[5];
  const float* gamma = (const float*)d_in[6];
  const float* beta  = (const float*)d_in[7];
  const float* lw    = (const float*)d_in[8];
  const float* lb    = (const float*)d_in[9];
  const int N = N_NODES, E = N_EDGES;
  const int* row = ei;
  const int* col = ei + E;

  char* ws = (char*)d_ws;
  size_t off = 0;
  auto alloc = [&](size_t bytes)->void*{
    void* p = ws + off; off = (off + bytes + 255) & ~(size_t)255; return p; };
  int*            deg   = (int*)   alloc((size_t)N*4);
  float*          dinv  = (float*) alloc((size_t)N*4);
  int*            offs  = (int*)   alloc((size_t)(N+1)*4);
  int*            cur   = (int*)   alloc((size_t)N*4);
  int*            bsums = (int*)   alloc(64*4);
  int2*           ep    = (int2*)  alloc((size_t)E*8);
  unsigned short* xbh   = (unsigned short*)alloc((size_t)N*128*2);
  unsigned short* xbl   = (unsigned short*)alloc((size_t)N*128*2);
  unsigned short* T1    = (unsigned short*)alloc((size_t)N*128*2);
  unsigned short* Ub    = (unsigned short*)alloc((size_t)N*128*2);
  unsigned short* H0h   = (unsigned short*)alloc((size_t)N*64*2);
  unsigned short* H0l   = (unsigned short*)alloc((size_t)N*64*2);
  unsigned short* H1h   = (unsigned short*)alloc((size_t)N*64*2);
  unsigned short* H1l   = (unsigned short*)alloc((size_t)N*64*2);
  float*          gbuf  = (float*) alloc((size_t)N*64*4);
  unsigned short* WTh   = (unsigned short*)alloc((size_t)135168*2);
  unsigned short* WTl   = (unsigned short*)alloc((size_t)135168*2);
  float*          stats = (float*) alloc((size_t)1280*4);

  hipMemsetAsync(deg, 0, (size_t)N*4, stream);
  hipMemsetAsync(stats, 0, (size_t)1280*4, stream);
  deg_count<<<(E+255)/256, 256, 0, stream>>>(row, deg, E);
  make_dinv<<<(N+255)/256, 256, 0, stream>>>(deg, dinv, N);
  int nb = (N+1023)/1024;
  scan_block<<<nb, 1024, 0, stream>>>(deg, offs, bsums, N);
  scan_bsums<<<1, 64, 0, stream>>>(bsums, nb);
  scan_fix<<<nb, 1024, 0, stream>>>(offs, cur, bsums, N, E);
  csr_fill<<<(E+255)/256, 256, 0, stream>>>(row, col, dinv, cur, ep, E);

  cast_x_split<<<((N*32)+255)/256, 256, 0, stream>>>((const float4*)x,
      (ushort4*)xbh, (ushort4*)xbl, N*32);
  transpose_w_split<<<(135168+255)/256, 256, 0, stream>>>(W1, Wr, WTh, WTl);

  // ---- layer 1 (SEGF=128): 16 rows/block ----
  spmm_bf16<128><<<(N+15)/16, 256, 0, stream>>>(offs, ep, xbh, T1, N);
  spmm_bf16<128><<<(N+15)/16, 256, 0, stream>>>(offs, ep, T1, Ub, N);
  gemm_mfma<128><<<(N+63)/64, 256, 0, stream>>>(xbh, xbl, T1, Ub, WTh, WTl,
      b1, gbuf, stats, N);
  bn_f32_split<<<((N*8)+255)/256, 256, 0, stream>>>(gbuf, H0h, H0l, stats, gamma, beta, N);

  // ---- layers 2..10 (SEGF=64): 32 rows/block ----
  unsigned short *hinh = H0h, *hinl = H0l, *houth = H1h, *houtl = H1l;
  for (int L=0; L<9; ++L){
    spmm_bf16<64><<<(N+31)/32, 256, 0, stream>>>(offs, ep, hinh, T1, N);
    spmm_bf16<64><<<(N+31)/32, 256, 0, stream>>>(offs, ep, T1, Ub, N);
    gemm_mfma<64><<<(N+63)/64, 256, 0, stream>>>(hinh, hinl, T1, Ub,
        WTh + 24576 + (size_t)L*12288, WTl + 24576 + (size_t)L*12288,
        br + (size_t)L*64, gbuf, stats + (size_t)(L+1)*128, N);
    bn_f32_split<<<((N*8)+255)/256, 256, 0, stream>>>(gbuf, houth, houtl,
        stats + (size_t)(L+1)*128, gamma + (size_t)(L+1)*64, beta + (size_t)(L+1)*64, N);
    unsigned short* t;
    t = hinh; hinh = houth; houth = t;
    t = hinl; hinl = houtl; houtl = t;
  }

  final_linear_split<<<(N+255)/256, 256, 0, stream>>>(hinh, hinl, lw, lb, (float*)d_out, N);
}

// Round 7
// 838.370 us; speedup vs baseline: 3.7203x; 1.3626x over previous
//
#include <hip/hip_runtime.h>
#include <hip/hip_bf16.h>

#define N_NODES 50000
#define N_EDGES 1200000
#define EPS_BN 1e-5f

typedef __attribute__((ext_vector_type(8))) short short8;
typedef __attribute__((ext_vector_type(4))) float f32x4;

union U16x8 { uint4 u; short8 s; };

__device__ __forceinline__ float lo2f(unsigned int u){ return __uint_as_float(u << 16); }
__device__ __forceinline__ float hi2f(unsigned int u){ return __uint_as_float(u & 0xffff0000u); }
__device__ __forceinline__ float b2f(unsigned short u){ return __uint_as_float(((unsigned int)u) << 16); }
__device__ __forceinline__ unsigned short f2b(float f){
  __hip_bfloat16 b = __float2bfloat16(f);
  return __builtin_bit_cast(unsigned short, b);
}

// ---------------- CSR build ----------------
__global__ void deg_count(const int* __restrict__ row, int* __restrict__ deg, int E){
  int e = blockIdx.x*256 + threadIdx.x;
  if (e < E) atomicAdd(&deg[row[e]], 1);
}

__global__ void make_dinv(const int* __restrict__ deg, float* __restrict__ dinv, int n){
  int i = blockIdx.x*256 + threadIdx.x;
  if (i < n){ int d = deg[i]; dinv[i] = (d>0) ? rsqrtf((float)d) : 0.f; }
}

__global__ void scan_block(const int* __restrict__ deg, int* __restrict__ offs,
                           int* __restrict__ bsums, int n){
  __shared__ int tmp[1024];
  int i = blockIdx.x*1024 + threadIdx.x;
  int v = (i<n) ? deg[i] : 0;
  tmp[threadIdx.x] = v;
  __syncthreads();
  for (int off=1; off<1024; off<<=1){
    int t = (threadIdx.x >= off) ? tmp[threadIdx.x-off] : 0;
    __syncthreads();
    tmp[threadIdx.x] += t;
    __syncthreads();
  }
  if (i<n) offs[i] = tmp[threadIdx.x] - v;
  if (threadIdx.x == 1023) bsums[blockIdx.x] = tmp[1023];
}

__global__ void scan_bsums(int* bsums, int nb){
  if (threadIdx.x==0 && blockIdx.x==0){
    int acc=0;
    for (int b=0;b<nb;b++){ int t=bsums[b]; bsums[b]=acc; acc+=t; }
  }
}

__global__ void scan_fix(int* __restrict__ offs, int* __restrict__ cur,
                         const int* __restrict__ bsums, int n, int E){
  int i = blockIdx.x*1024 + threadIdx.x;
  if (i<n){
    int o = offs[i] + bsums[blockIdx.x];
    offs[i] = o; cur[i] = o;
  }
  if (i==0) offs[n] = E;
}

__global__ void csr_fill(const int* __restrict__ row, const int* __restrict__ col,
                         const float* __restrict__ dinv, int* __restrict__ cur,
                         int2* __restrict__ ep, int E){
  int e = blockIdx.x*256 + threadIdx.x;
  if (e>=E) return;
  int r = row[e], c = col[e];
  int pos = atomicAdd(&cur[r], 1);
  float w = -dinv[r]*dinv[c];
  ep[pos] = make_int2(c, __float_as_int(w));
}

// ---------------- prep: x -> bf16 hi/lo planes ----------------
__global__ void cast_x_split(const float4* __restrict__ x, ushort4* __restrict__ xh,
                             ushort4* __restrict__ xl, int n4){
  int t = blockIdx.x*256 + threadIdx.x;
  if (t >= n4) return;
  float4 v = x[t];
  ushort4 h, l;
  h.x = f2b(v.x); l.x = f2b(v.x - b2f(h.x));
  h.y = f2b(v.y); l.y = f2b(v.y - b2f(h.y));
  h.z = f2b(v.z); l.z = f2b(v.z - b2f(h.z));
  h.w = f2b(v.w); l.w = f2b(v.w - b2f(h.w));
  xh[t] = h; xl[t] = l;
}

// ---- weights: fold (W0-W2, W1, 2*W2), transpose to [64][K], split hi/lo ----
__global__ void transpose_w_split(const float* __restrict__ W1, const float* __restrict__ Wr,
                                  unsigned short* __restrict__ WTh,
                                  unsigned short* __restrict__ WTl){
  int t = blockIdx.x*256 + threadIdx.x;
  float val;
  if (t < 24576){
    int c = t/384, kk = t%384;
    int seg = kk/128, f = kk%128;
    if (seg==0)      val = W1[(size_t)f*64 + c] - W1[(size_t)(256+f)*64 + c];
    else if (seg==1) val = W1[(size_t)(128+f)*64 + c];
    else             val = 2.f * W1[(size_t)(256+f)*64 + c];
  } else if (t < 135168){
    int u = t - 24576;
    int L = u/12288, r2 = u%12288;
    int c = r2/192, kk = r2%192;
    int seg = kk/64, f = kk%64;
    const float* WL = Wr + (size_t)L*12288;
    if (seg==0)      val = WL[(size_t)f*64 + c] - WL[(size_t)(128+f)*64 + c];
    else if (seg==1) val = WL[(size_t)(64+f)*64 + c];
    else             val = 2.f * WL[(size_t)(128+f)*64 + c];
  } else return;
  unsigned short h = f2b(val);
  WTh[t] = h;
  WTl[t] = f2b(val - b2f(h));
}

// ---------------- SpMM: dst = Lhat @ src ----------------
__device__ __forceinline__ void spmm_acc8(float wt, uint4 u, float* a){
  a[0] = fmaf(wt, lo2f(u.x), a[0]);
  a[1] = fmaf(wt, hi2f(u.x), a[1]);
  a[2] = fmaf(wt, lo2f(u.y), a[2]);
  a[3] = fmaf(wt, hi2f(u.y), a[3]);
  a[4] = fmaf(wt, lo2f(u.z), a[4]);
  a[5] = fmaf(wt, hi2f(u.z), a[5]);
  a[6] = fmaf(wt, lo2f(u.w), a[6]);
  a[7] = fmaf(wt, hi2f(u.w), a[7]);
}

template<int F>
__global__ void spmm_bf16(const int* __restrict__ offs, const int2* __restrict__ ep,
                          const unsigned short* __restrict__ src,
                          unsigned short* __restrict__ dst, int n){
  constexpr int LPR = F/8;
  constexpr int RPW = 64/LPR;
  int lane = threadIdx.x & 63;
  int wv = threadIdx.x >> 6;
  int lr = lane / LPR;
  int li = lane % LPR;
  int row = (blockIdx.x*4 + wv)*RPW + lr;
  int s = 0, e = 0;
  if (row < n){ s = offs[row]; e = offs[row+1]; }
  float a[8];
  #pragma unroll
  for (int c=0;c<8;c++) a[c]=0.f;
  const int fb = li*8;
  int j = s;
  for (; j+4 <= e; j += 4){
    int2 q0 = ep[j+0];
    int2 q1 = ep[j+1];
    int2 q2 = ep[j+2];
    int2 q3 = ep[j+3];
    uint4 u0 = *(const uint4*)(src + (size_t)q0.x*F + fb);
    uint4 u1 = *(const uint4*)(src + (size_t)q1.x*F + fb);
    uint4 u2 = *(const uint4*)(src + (size_t)q2.x*F + fb);
    uint4 u3 = *(const uint4*)(src + (size_t)q3.x*F + fb);
    spmm_acc8(__int_as_float(q0.y), u0, a);
    spmm_acc8(__int_as_float(q1.y), u1, a);
    spmm_acc8(__int_as_float(q2.y), u2, a);
    spmm_acc8(__int_as_float(q3.y), u3, a);
  }
  for (; j < e; ++j){
    int2 q = ep[j];
    uint4 u = *(const uint4*)(src + (size_t)q.x*F + fb);
    spmm_acc8(__int_as_float(q.y), u, a);
  }
  if (row < n){
    uint4 o;
    o.x = (unsigned int)f2b(a[0]) | ((unsigned int)f2b(a[1]) << 16);
    o.y = (unsigned int)f2b(a[2]) | ((unsigned int)f2b(a[3]) << 16);
    o.z = (unsigned int)f2b(a[4]) | ((unsigned int)f2b(a[5]) << 16);
    o.w = (unsigned int)f2b(a[6]) | ((unsigned int)f2b(a[7]) << 16);
    *(uint4*)(dst + (size_t)row*F + fb) = o;
  }
}

// ---- MFMA GEMM; W staged per-seg in LDS (XOR-swizzled), stats -> 16 replica slots ----
template<int SEGF>
__global__ void gemm_mfma(const unsigned short* __restrict__ A0h,
                          const unsigned short* __restrict__ A0l,
                          const unsigned short* __restrict__ A1,
                          const unsigned short* __restrict__ A2,
                          const unsigned short* __restrict__ WTh,   // [64][K]
                          const unsigned short* __restrict__ WTl,
                          const float* __restrict__ bias,
                          float* __restrict__ out,
                          float* __restrict__ stats, int n){
  constexpr int K = 3*SEGF;
  constexpr int KPS = SEGF/32;
  constexpr int CHUNKS = 16*SEGF;       // 16B chunks per seg stage (2 planes)
  constexpr int PLANE_CH = 8*SEGF;      // chunks per plane
  __shared__ unsigned short wlds[2*64*SEGF];
  __shared__ float ssum[64];
  __shared__ float ssq[64];
  if (threadIdx.x < 64){ ssum[threadIdx.x] = 0.f; ssq[threadIdx.x] = 0.f; }

  int lane = threadIdx.x & 63;
  int wv = threadIdx.x >> 6;
  int mrow = lane & 15;
  int kg = lane >> 4;
  int brow = blockIdx.x*64 + wv*16;
  int m = brow + mrow;
  bool mv = m < n;

  f32x4 acc[4];
  #pragma unroll
  for (int t=0;t<4;t++) acc[t] = f32x4{0.f,0.f,0.f,0.f};

  #pragma unroll
  for (int seg=0; seg<3; ++seg){
    const unsigned short* Ah = (seg==0) ? A0h : (seg==1) ? A1 : A2;
    // stage this seg's W (hi+lo) into LDS, swizzled
    #pragma unroll
    for (int c0=0; c0<CHUNKS; c0+=256){
      int c = c0 + threadIdx.x;
      int plane = c / PLANE_CH;
      int r = c % PLANE_CH;
      int col = r / (SEGF/8);
      int k8 = r % (SEGF/8);
      const unsigned short* srcp = (plane ? WTl : WTh) + (size_t)col*K + seg*SEGF + k8*8;
      uint4 v = *(const uint4*)srcp;
      int byte = ((plane*64 + col)*SEGF + k8*8)*2;
      byte ^= (col & 7) << 4;
      *(uint4*)((char*)wlds + byte) = v;
    }
    // preload A fragments for this seg
    U16x8 afh[KPS], afl[KPS];
    #pragma unroll
    for (int kk=0; kk<KPS; ++kk){
      if (mv) afh[kk].u = *(const uint4*)(Ah + (size_t)m*SEGF + kk*32 + kg*8);
      else    afh[kk].u = make_uint4(0,0,0,0);
      if (seg==0){
        if (mv) afl[kk].u = *(const uint4*)(A0l + (size_t)m*SEGF + kk*32 + kg*8);
        else    afl[kk].u = make_uint4(0,0,0,0);
      }
    }
    __syncthreads();
    #pragma unroll
    for (int kk=0; kk<KPS; ++kk){
      #pragma unroll
      for (int t=0;t<4;t++){
        int col = t*16 + mrow;
        int koff = kk*32 + kg*8;
        int byteh = (col*SEGF + koff)*2;          byteh ^= (col & 7) << 4;
        int bytel = ((64 + col)*SEGF + koff)*2;   bytel ^= (col & 7) << 4;
        U16x8 bh, bl;
        bh.u = *(const uint4*)((const char*)wlds + byteh);
        bl.u = *(const uint4*)((const char*)wlds + bytel);
        acc[t] = __builtin_amdgcn_mfma_f32_16x16x32_bf16(afh[kk].s, bh.s, acc[t], 0, 0, 0);
        acc[t] = __builtin_amdgcn_mfma_f32_16x16x32_bf16(afh[kk].s, bl.s, acc[t], 0, 0, 0);
        if (seg==0)
          acc[t] = __builtin_amdgcn_mfma_f32_16x16x32_bf16(afl[kk].s, bh.s, acc[t], 0, 0, 0);
      }
    }
    __syncthreads();
  }

  #pragma unroll
  for (int t=0;t<4;t++){
    int col = t*16 + mrow;
    float bsv = bias[col];
    float s = 0.f, sq = 0.f;
    #pragma unroll
    for (int i=0;i<4;i++){
      int r = brow + kg*4 + i;
      float v = fmaxf(acc[t][i] + bsv, 0.f);
      if (r < n){
        out[(size_t)r*64 + col] = v;
        s += v; sq += v*v;
      }
    }
    s  += __shfl_xor(s, 16);  sq += __shfl_xor(sq, 16);
    s  += __shfl_xor(s, 32);  sq += __shfl_xor(sq, 32);
    if (kg == 0){
      atomicAdd(&ssum[col], s);
      atomicAdd(&ssq[col], sq);
    }
  }
  __syncthreads();
  if (threadIdx.x < 64){
    float* sl = stats + (blockIdx.x & 15)*128;
    atomicAdd(&sl[threadIdx.x], ssum[threadIdx.x]);
    atomicAdd(&sl[64+threadIdx.x], ssq[threadIdx.x]);
  }
}

// ---------------- BN: reduce 16 stat replicas, fp32 in, bf16 hi/lo out ----------------
__global__ void bn_f32_split(const float* __restrict__ g_in,
                             unsigned short* __restrict__ hh, unsigned short* __restrict__ hl,
                             const float* __restrict__ stats,
                             const float* __restrict__ gamma, const float* __restrict__ beta,
                             int n){
  __shared__ float red[128];
  __shared__ float sc[64], sh[64];
  int tid = threadIdx.x;
  if (tid < 128){
    float s = 0.f;
    #pragma unroll
    for (int r=0;r<16;r++) s += stats[r*128 + tid];
    red[tid] = s;
  }
  __syncthreads();
  if (tid < 64){
    float inv_n = 1.f/(float)n;
    float mu = red[tid]*inv_n;
    float var = red[64+tid]*inv_n - mu*mu;
    float a = gamma[tid]*rsqrtf(var + EPS_BN);
    sc[tid] = a;
    sh[tid] = beta[tid] - mu*a;
  }
  __syncthreads();
  int t = blockIdx.x*256 + tid;
  if (t >= n*8) return;
  int fb = (t & 7)*8;
  int node = t >> 3;
  const float* gp = g_in + (size_t)node*64 + fb;
  float4 v0 = *(const float4*)gp;
  float4 v1 = *(const float4*)(gp + 4);
  float vv[8] = {v0.x, v0.y, v0.z, v0.w, v1.x, v1.y, v1.z, v1.w};
  unsigned int oh[4], ol[4];
  #pragma unroll
  for (int p=0;p<4;p++){
    int f0 = fb + 2*p, f1 = f0 + 1;
    float y0 = fmaf(vv[2*p],   sc[f0], sh[f0]);
    float y1 = fmaf(vv[2*p+1], sc[f1], sh[f1]);
    unsigned short h0 = f2b(y0), h1 = f2b(y1);
    unsigned short l0 = f2b(y0 - b2f(h0)), l1 = f2b(y1 - b2f(h1));
    oh[p] = (unsigned int)h0 | ((unsigned int)h1 << 16);
    ol[p] = (unsigned int)l0 | ((unsigned int)l1 << 16);
  }
  ((uint4*)hh)[t] = make_uint4(oh[0], oh[1], oh[2], oh[3]);
  ((uint4*)hl)[t] = make_uint4(ol[0], ol[1], ol[2], ol[3]);
}

// ---------------- final linear 64 -> 2 ----------------
__global__ void final_linear_split(const unsigned short* __restrict__ hh,
                                   const unsigned short* __restrict__ hl,
                                   const float* __restrict__ w, const float* __restrict__ b,
                                   float* __restrict__ out, int n){
  int i = blockIdx.x*256 + threadIdx.x;
  if (i >= n) return;
  float a0 = b[0], a1 = b[1];
  const unsigned int* hp = (const unsigned int*)(hh + (size_t)i*64);
  const unsigned int* lp = (const unsigned int*)(hl + (size_t)i*64);
  #pragma unroll
  for (int k=0;k<32;k++){
    unsigned int uh = hp[k], ul = lp[k];
    float v0 = lo2f(uh) + lo2f(ul);
    float v1 = hi2f(uh) + hi2f(ul);
    a0 = fmaf(v0, w[(2*k)*2+0], a0);
    a1 = fmaf(v0, w[(2*k)*2+1], a1);
    a0 = fmaf(v1, w[(2*k+1)*2+0], a0);
    a1 = fmaf(v1, w[(2*k+1)*2+1], a1);
  }
  out[i*2+0] = a0;
  out[i*2+1] = a1;
}

extern "C" void kernel_launch(void* const* d_in, const int* in_sizes, int n_in,
                              void* d_out, int out_size, void* d_ws, size_t ws_size,
                              hipStream_t stream){
  const float* x     = (const float*)d_in[0];
  const int*   ei    = (const int*)d_in[1];
  const float* W1    = (const float*)d_in[2];
  const float* b1    = (const float*)d_in[3];
  const float* Wr    = (const float*)d_in[4];
  const float* br    = (const float*)d_in[5];
  const float* gamma = (const float*)d_in[6];
  const float* beta  = (const float*)d_in[7];
  const float* lw    = (const float*)d_in[8];
  const float* lb    = (const float*)d_in[9];
  const int N = N_NODES, E = N_EDGES;
  const int* row = ei;
  const int* col = ei + E;

  char* ws = (char*)d_ws;
  size_t off = 0;
  auto alloc = [&](size_t bytes)->void*{
    void* p = ws + off; off = (off + bytes + 255) & ~(size_t)255; return p; };
  int*            deg   = (int*)   alloc((size_t)N*4);
  float*          dinv  = (float*) alloc((size_t)N*4);
  int*            offs  = (int*)   alloc((size_t)(N+1)*4);
  int*            cur   = (int*)   alloc((size_t)N*4);
  int*            bsums = (int*)   alloc(64*4);
  int2*           ep    = (int2*)  alloc((size_t)E*8);
  unsigned short* xbh   = (unsigned short*)alloc((size_t)N*128*2);
  unsigned short* xbl   = (unsigned short*)alloc((size_t)N*128*2);
  unsigned short* T1    = (unsigned short*)alloc((size_t)N*128*2);
  unsigned short* Ub    = (unsigned short*)alloc((size_t)N*128*2);
  unsigned short* H0h   = (unsigned short*)alloc((size_t)N*64*2);
  unsigned short* H0l   = (unsigned short*)alloc((size_t)N*64*2);
  unsigned short* H1h   = (unsigned short*)alloc((size_t)N*64*2);
  unsigned short* H1l   = (unsigned short*)alloc((size_t)N*64*2);
  float*          gbuf  = (float*) alloc((size_t)N*64*4);
  unsigned short* WTh   = (unsigned short*)alloc((size_t)135168*2);
  unsigned short* WTl   = (unsigned short*)alloc((size_t)135168*2);
  float*          stats = (float*) alloc((size_t)10*2048*4);   // 10 layers x 16 reps x 128

  hipMemsetAsync(deg, 0, (size_t)N*4, stream);
  hipMemsetAsync(stats, 0, (size_t)10*2048*4, stream);
  deg_count<<<(E+255)/256, 256, 0, stream>>>(row, deg, E);
  make_dinv<<<(N+255)/256, 256, 0, stream>>>(deg, dinv, N);
  int nb = (N+1023)/1024;
  scan_block<<<nb, 1024, 0, stream>>>(deg, offs, bsums, N);
  scan_bsums<<<1, 64, 0, stream>>>(bsums, nb);
  scan_fix<<<nb, 1024, 0, stream>>>(offs, cur, bsums, N, E);
  csr_fill<<<(E+255)/256, 256, 0, stream>>>(row, col, dinv, cur, ep, E);

  cast_x_split<<<((N*32)+255)/256, 256, 0, stream>>>((const float4*)x,
      (ushort4*)xbh, (ushort4*)xbl, N*32);
  transpose_w_split<<<(135168+255)/256, 256, 0, stream>>>(W1, Wr, WTh, WTl);

  // ---- layer 1 (SEGF=128) ----
  spmm_bf16<128><<<(N+15)/16, 256, 0, stream>>>(offs, ep, xbh, T1, N);
  spmm_bf16<128><<<(N+15)/16, 256, 0, stream>>>(offs, ep, T1, Ub, N);
  gemm_mfma<128><<<(N+63)/64, 256, 0, stream>>>(xbh, xbl, T1, Ub, WTh, WTl,
      b1, gbuf, stats, N);
  bn_f32_split<<<((N*8)+255)/256, 256, 0, stream>>>(gbuf, H0h, H0l, stats, gamma, beta, N);

  // ---- layers 2..10 (SEGF=64) ----
  unsigned short *hinh = H0h, *hinl = H0l, *houth = H1h, *houtl = H1l;
  for (int L=0; L<9; ++L){
    spmm_bf16<64><<<(N+31)/32, 256, 0, stream>>>(offs, ep, hinh, T1, N);
    spmm_bf16<64><<<(N+31)/32, 256, 0, stream>>>(offs, ep, T1, Ub, N);
    gemm_mfma<64><<<(N+63)/64, 256, 0, stream>>>(hinh, hinl, T1, Ub,
        WTh + 24576 + (size_t)L*12288, WTl + 24576 + (size_t)L*12288,
        br + (size_t)L*64, gbuf, stats + (size_t)(L+1)*2048, N);
    bn_f32_split<<<((N*8)+255)/256, 256, 0, stream>>>(gbuf, houth, houtl,
        stats + (size_t)(L+1)*2048, gamma + (size_t)(L+1)*64, beta + (size_t)(L+1)*64, N);
    unsigned short* t;
    t = hinh; hinh = houth; houth = t;
    t = hinl; hinl = houtl; houtl = t;
  }

  final_linear_split<<<(N+255)/256, 256, 0, stream>>>(hinh, hinl, lw, lb, (float*)d_out, N);
}

// Round 8
// 808.494 us; speedup vs baseline: 3.8578x; 1.0370x over previous
//
#include <hip/hip_runtime.h>
#include <hip/hip_bf16.h>

#define N_NODES 50000
#define N_EDGES 1200000
#define EPS_BN 1e-5f

typedef __attribute__((ext_vector_type(8))) short short8;
typedef __attribute__((ext_vector_type(4))) float f32x4;

union U16x8 { uint4 u; short8 s; };

__device__ __forceinline__ float lo2f(unsigned int u){ return __uint_as_float(u << 16); }
__device__ __forceinline__ float hi2f(unsigned int u){ return __uint_as_float(u & 0xffff0000u); }
__device__ __forceinline__ float b2f(unsigned short u){ return __uint_as_float(((unsigned int)u) << 16); }
__device__ __forceinline__ unsigned short f2b(float f){
  __hip_bfloat16 b = __float2bfloat16(f);
  return __builtin_bit_cast(unsigned short, b);
}

// ---------------- CSR build ----------------
__global__ void deg_count(const int* __restrict__ row, int* __restrict__ deg, int E){
  int e = blockIdx.x*256 + threadIdx.x;
  if (e < E) atomicAdd(&deg[row[e]], 1);
}

__global__ void make_dinv(const int* __restrict__ deg, float* __restrict__ dinv, int n){
  int i = blockIdx.x*256 + threadIdx.x;
  if (i < n){ int d = deg[i]; dinv[i] = (d>0) ? rsqrtf((float)d) : 0.f; }
}

__global__ void scan_block(const int* __restrict__ deg, int* __restrict__ offs,
                           int* __restrict__ bsums, int n){
  __shared__ int tmp[1024];
  int i = blockIdx.x*1024 + threadIdx.x;
  int v = (i<n) ? deg[i] : 0;
  tmp[threadIdx.x] = v;
  __syncthreads();
  for (int off=1; off<1024; off<<=1){
    int t = (threadIdx.x >= off) ? tmp[threadIdx.x-off] : 0;
    __syncthreads();
    tmp[threadIdx.x] += t;
    __syncthreads();
  }
  if (i<n) offs[i] = tmp[threadIdx.x] - v;
  if (threadIdx.x == 1023) bsums[blockIdx.x] = tmp[1023];
}

__global__ void scan_bsums(int* bsums, int nb){
  if (threadIdx.x==0 && blockIdx.x==0){
    int acc=0;
    for (int b=0;b<nb;b++){ int t=bsums[b]; bsums[b]=acc; acc+=t; }
  }
}

__global__ void scan_fix(int* __restrict__ offs, int* __restrict__ cur,
                         const int* __restrict__ bsums, int n, int E){
  int i = blockIdx.x*1024 + threadIdx.x;
  if (i<n){
    int o = offs[i] + bsums[blockIdx.x];
    offs[i] = o; cur[i] = o;
  }
  if (i==0) offs[n] = E;
}

// edge record = 4B col only (weight folded into pre-scaled features)
__global__ void csr_fill(const int* __restrict__ row, const int* __restrict__ col,
                         int* __restrict__ cur, int* __restrict__ ep, int E){
  int e = blockIdx.x*256 + threadIdx.x;
  if (e>=E) return;
  int r = row[e];
  int pos = atomicAdd(&cur[r], 1);
  ep[pos] = col[e];
}

// ---------------- prep: xs = dinv[node]*x bf16 (gather source for layer-1 spmm) ----------------
__global__ void cast_xs(const float* __restrict__ x, const float* __restrict__ dinv,
                        uint4* __restrict__ xs, int n){
  int t = blockIdx.x*256 + threadIdx.x;
  if (t >= n*16) return;
  int node = t >> 4;
  int fb = (t & 15)*8;
  float dv = dinv[node];
  const float* xp = x + (size_t)node*128 + fb;
  float4 v0 = *(const float4*)xp;
  float4 v1 = *(const float4*)(xp+4);
  float vv[8] = {v0.x,v0.y,v0.z,v0.w,v1.x,v1.y,v1.z,v1.w};
  uint4 o;
  unsigned int* op = (unsigned int*)&o;
  #pragma unroll
  for (int p=0;p<4;p++){
    op[p] = (unsigned int)f2b(dv*vv[2*p]) | ((unsigned int)f2b(dv*vv[2*p+1]) << 16);
  }
  xs[t] = o;
}

// ---- weights: fold (W0-W2, W1, 2*W2), transpose to [64][K], split hi/lo ----
__global__ void transpose_w_split(const float* __restrict__ W1, const float* __restrict__ Wr,
                                  unsigned short* __restrict__ WTh,
                                  unsigned short* __restrict__ WTl){
  int t = blockIdx.x*256 + threadIdx.x;
  float val;
  if (t < 24576){
    int c = t/384, kk = t%384;
    int seg = kk/128, f = kk%128;
    if (seg==0)      val = W1[(size_t)f*64 + c] - W1[(size_t)(256+f)*64 + c];
    else if (seg==1) val = W1[(size_t)(128+f)*64 + c];
    else             val = 2.f * W1[(size_t)(256+f)*64 + c];
  } else if (t < 135168){
    int u = t - 24576;
    int L = u/12288, r2 = u%12288;
    int c = r2/192, kk = r2%192;
    int seg = kk/64, f = kk%64;
    const float* WL = Wr + (size_t)L*12288;
    if (seg==0)      val = WL[(size_t)f*64 + c] - WL[(size_t)(128+f)*64 + c];
    else if (seg==1) val = WL[(size_t)(64+f)*64 + c];
    else             val = 2.f * WL[(size_t)(128+f)*64 + c];
  } else return;
  unsigned short h = f2b(val);
  WTh[t] = h;
  WTl[t] = f2b(val - b2f(h));
}

// ---------------- SpMM: gathers pre-scaled src; out_u = -dinv[r]*acc; out_s = dinv[r]*out_u ----------------
__device__ __forceinline__ void spmm_acc8(uint4 u, float* a){
  a[0] += lo2f(u.x);
  a[1] += hi2f(u.x);
  a[2] += lo2f(u.y);
  a[3] += hi2f(u.y);
  a[4] += lo2f(u.z);
  a[5] += hi2f(u.z);
  a[6] += lo2f(u.w);
  a[7] += hi2f(u.w);
}

template<int F, bool BOTH>
__global__ void spmm_bf16(const int* __restrict__ offs, const int* __restrict__ ep,
                          const float* __restrict__ dinv,
                          const unsigned short* __restrict__ src,
                          unsigned short* __restrict__ dst_u,
                          unsigned short* __restrict__ dst_s, int n){
  constexpr int LPR = F/8;
  constexpr int RPW = 64/LPR;
  int lane = threadIdx.x & 63;
  int wv = threadIdx.x >> 6;
  int lr = lane / LPR;
  int li = lane % LPR;
  int row = (blockIdx.x*4 + wv)*RPW + lr;
  int s = 0, e = 0;
  if (row < n){ s = offs[row]; e = offs[row+1]; }
  float a[8];
  #pragma unroll
  for (int c=0;c<8;c++) a[c]=0.f;
  const int fb = li*8;
  int j = s;
  for (; j+4 <= e; j += 4){
    int c0 = ep[j+0];
    int c1 = ep[j+1];
    int c2 = ep[j+2];
    int c3 = ep[j+3];
    uint4 u0 = *(const uint4*)(src + (size_t)c0*F + fb);
    uint4 u1 = *(const uint4*)(src + (size_t)c1*F + fb);
    uint4 u2 = *(const uint4*)(src + (size_t)c2*F + fb);
    uint4 u3 = *(const uint4*)(src + (size_t)c3*F + fb);
    spmm_acc8(u0, a);
    spmm_acc8(u1, a);
    spmm_acc8(u2, a);
    spmm_acc8(u3, a);
  }
  for (; j < e; ++j){
    uint4 u = *(const uint4*)(src + (size_t)ep[j]*F + fb);
    spmm_acc8(u, a);
  }
  if (row < n){
    float dv = dinv[row];
    float uvals[8];
    #pragma unroll
    for (int c=0;c<8;c++) uvals[c] = -dv * a[c];
    uint4 ou;
    unsigned int* oup = (unsigned int*)&ou;
    #pragma unroll
    for (int p=0;p<4;p++)
      oup[p] = (unsigned int)f2b(uvals[2*p]) | ((unsigned int)f2b(uvals[2*p+1]) << 16);
    *(uint4*)(dst_u + (size_t)row*F + fb) = ou;
    if (BOTH){
      uint4 os;
      unsigned int* osp = (unsigned int*)&os;
      #pragma unroll
      for (int p=0;p<4;p++)
        osp[p] = (unsigned int)f2b(dv*uvals[2*p]) | ((unsigned int)f2b(dv*uvals[2*p+1]) << 16);
      *(uint4*)(dst_s + (size_t)row*F + fb) = os;
    }
  }
}

// ---- MFMA GEMM; A0 = fp32 source with inline affine (BN of prev layer or identity) ----
// A0 contributes hi+lo planes; A1/A2 single bf16; W hi/lo staged in LDS (XOR swizzle).
template<int SEGF>
__global__ void gemm_mfma(const float* __restrict__ A0f,
                          const float* __restrict__ scsh,   // [128] sc|sh, or nullptr=identity
                          const unsigned short* __restrict__ A1,
                          const unsigned short* __restrict__ A2,
                          const unsigned short* __restrict__ WTh,   // [64][K]
                          const unsigned short* __restrict__ WTl,
                          const float* __restrict__ bias,
                          float* __restrict__ out,
                          float* __restrict__ stats, int n){
  constexpr int K = 3*SEGF;
  constexpr int KPS = SEGF/32;
  constexpr int CHUNKS = 16*SEGF;
  constexpr int PLANE_CH = 8*SEGF;
  __shared__ unsigned short wlds[2*64*SEGF];
  __shared__ float ssum[64];
  __shared__ float ssq[64];
  __shared__ float sc_l[128];   // sc|sh (sc=1,sh=0 if identity); SEGF<=128 features
  __shared__ float sh_l[128];
  if (threadIdx.x < 64){ ssum[threadIdx.x] = 0.f; ssq[threadIdx.x] = 0.f; }
  if (threadIdx.x < SEGF){
    if (scsh){
      sc_l[threadIdx.x] = scsh[threadIdx.x];
      sh_l[threadIdx.x] = scsh[64 + threadIdx.x];
    } else {
      sc_l[threadIdx.x] = 1.f;
      sh_l[threadIdx.x] = 0.f;
    }
  }

  int lane = threadIdx.x & 63;
  int wv = threadIdx.x >> 6;
  int mrow = lane & 15;
  int kg = lane >> 4;
  int brow = blockIdx.x*64 + wv*16;
  int m = brow + mrow;
  bool mv = m < n;

  f32x4 acc[4];
  #pragma unroll
  for (int t=0;t<4;t++) acc[t] = f32x4{0.f,0.f,0.f,0.f};

  #pragma unroll
  for (int seg=0; seg<3; ++seg){
    // stage this seg's W (hi+lo) into LDS, swizzled
    #pragma unroll
    for (int c0=0; c0<CHUNKS; c0+=256){
      int c = c0 + threadIdx.x;
      int plane = c / PLANE_CH;
      int r = c % PLANE_CH;
      int col = r / (SEGF/8);
      int k8 = r % (SEGF/8);
      const unsigned short* srcp = (plane ? WTl : WTh) + (size_t)col*K + seg*SEGF + k8*8;
      uint4 v = *(const uint4*)srcp;
      int byte = ((plane*64 + col)*SEGF + k8*8)*2;
      byte ^= (col & 7) << 4;
      *(uint4*)((char*)wlds + byte) = v;
    }
    // preload A fragments for this seg
    U16x8 afh[KPS], afl[KPS];
    #pragma unroll
    for (int kk=0; kk<KPS; ++kk){
      int koff = kk*32 + kg*8;
      if (seg==0){
        // fp32 source + affine -> hi/lo bf16 fragments
        float y[8];
        if (mv){
          const float* gp = A0f + (size_t)m*SEGF + koff;
          float4 v0 = *(const float4*)gp;
          float4 v1 = *(const float4*)(gp+4);
          float g[8] = {v0.x,v0.y,v0.z,v0.w,v1.x,v1.y,v1.z,v1.w};
          #pragma unroll
          for (int i=0;i<8;i++){
            int f = koff + i;
            y[i] = fmaf(g[i], sc_l[f], sh_l[f]);
          }
        } else {
          #pragma unroll
          for (int i=0;i<8;i++) y[i] = 0.f;
        }
        unsigned int* hp = (unsigned int*)&afh[kk].u;
        unsigned int* lp = (unsigned int*)&afl[kk].u;
        #pragma unroll
        for (int p=0;p<4;p++){
          unsigned short h0 = f2b(y[2*p]),  h1 = f2b(y[2*p+1]);
          unsigned short l0 = f2b(y[2*p] - b2f(h0)), l1 = f2b(y[2*p+1] - b2f(h1));
          hp[p] = (unsigned int)h0 | ((unsigned int)h1 << 16);
          lp[p] = (unsigned int)l0 | ((unsigned int)l1 << 16);
        }
      } else {
        const unsigned short* Ah = (seg==1) ? A1 : A2;
        if (mv) afh[kk].u = *(const uint4*)(Ah + (size_t)m*SEGF + koff);
        else    afh[kk].u = make_uint4(0,0,0,0);
      }
    }
    __syncthreads();
    #pragma unroll
    for (int kk=0; kk<KPS; ++kk){
      #pragma unroll
      for (int t=0;t<4;t++){
        int col = t*16 + mrow;
        int koff = kk*32 + kg*8;
        int byteh = (col*SEGF + koff)*2;          byteh ^= (col & 7) << 4;
        int bytel = ((64 + col)*SEGF + koff)*2;   bytel ^= (col & 7) << 4;
        U16x8 bh, bl;
        bh.u = *(const uint4*)((const char*)wlds + byteh);
        bl.u = *(const uint4*)((const char*)wlds + bytel);
        acc[t] = __builtin_amdgcn_mfma_f32_16x16x32_bf16(afh[kk].s, bh.s, acc[t], 0, 0, 0);
        acc[t] = __builtin_amdgcn_mfma_f32_16x16x32_bf16(afh[kk].s, bl.s, acc[t], 0, 0, 0);
        if (seg==0)
          acc[t] = __builtin_amdgcn_mfma_f32_16x16x32_bf16(afl[kk].s, bh.s, acc[t], 0, 0, 0);
      }
    }
    __syncthreads();
  }

  #pragma unroll
  for (int t=0;t<4;t++){
    int col = t*16 + mrow;
    float bsv = bias[col];
    float s = 0.f, sq = 0.f;
    #pragma unroll
    for (int i=0;i<4;i++){
      int r = brow + kg*4 + i;
      float v = fmaxf(acc[t][i] + bsv, 0.f);
      if (r < n){
        out[(size_t)r*64 + col] = v;
        s += v; sq += v*v;
      }
    }
    s  += __shfl_xor(s, 16);  sq += __shfl_xor(sq, 16);
    s  += __shfl_xor(s, 32);  sq += __shfl_xor(sq, 32);
    if (kg == 0){
      atomicAdd(&ssum[col], s);
      atomicAdd(&ssq[col], sq);
    }
  }
  __syncthreads();
  if (threadIdx.x < 64){
    float* sl = stats + (blockIdx.x & 15)*128;
    atomicAdd(&sl[threadIdx.x], ssum[threadIdx.x]);
    atomicAdd(&sl[64+threadIdx.x], ssq[threadIdx.x]);
  }
}

// ---- BN-scale: reduce stats -> sc/sh (block 0 writes scsh); hs = dinv[node]*(sc*g+sh) bf16 ----
__global__ void bn_scale(const float* __restrict__ g_in, const float* __restrict__ dinv,
                         unsigned short* __restrict__ hs,
                         const float* __restrict__ stats, float* __restrict__ scsh,
                         const float* __restrict__ gamma, const float* __restrict__ beta,
                         int n){
  __shared__ float red[128];
  __shared__ float sc[64], sh[64];
  int tid = threadIdx.x;
  if (tid < 128){
    float s = 0.f;
    #pragma unroll
    for (int r=0;r<16;r++) s += stats[r*128 + tid];
    red[tid] = s;
  }
  __syncthreads();
  if (tid < 64){
    float inv_n = 1.f/(float)n;
    float mu = red[tid]*inv_n;
    float var = red[64+tid]*inv_n - mu*mu;
    float a = gamma[tid]*rsqrtf(var + EPS_BN);
    sc[tid] = a;
    sh[tid] = beta[tid] - mu*a;
    if (blockIdx.x == 0){
      scsh[tid] = a;
      scsh[64+tid] = sh[tid];
    }
  }
  __syncthreads();
  int t = blockIdx.x*256 + tid;
  if (t >= n*8) return;
  int fb = (t & 7)*8;
  int node = t >> 3;
  float dv = dinv[node];
  const float* gp = g_in + (size_t)node*64 + fb;
  float4 v0 = *(const float4*)gp;
  float4 v1 = *(const float4*)(gp + 4);
  float vv[8] = {v0.x, v0.y, v0.z, v0.w, v1.x, v1.y, v1.z, v1.w};
  uint4 o;
  unsigned int* op = (unsigned int*)&o;
  #pragma unroll
  for (int p=0;p<4;p++){
    int f0 = fb + 2*p, f1 = f0 + 1;
    float y0 = dv * fmaf(vv[2*p],   sc[f0], sh[f0]);
    float y1 = dv * fmaf(vv[2*p+1], sc[f1], sh[f1]);
    op[p] = (unsigned int)f2b(y0) | ((unsigned int)f2b(y1) << 16);
  }
  ((uint4*)hs)[t] = o;
}

// ---------------- final: BN(layer10) in fp32 + linear 64->2 ----------------
__global__ void final_linear_bn(const float* __restrict__ g_in,
                                const float* __restrict__ stats,
                                const float* __restrict__ gamma, const float* __restrict__ beta,
                                const float* __restrict__ w, const float* __restrict__ b,
                                float* __restrict__ out, int n){
  __shared__ float red[128];
  __shared__ float sc[64], sh[64];
  int tid = threadIdx.x;
  if (tid < 128){
    float s = 0.f;
    #pragma unroll
    for (int r=0;r<16;r++) s += stats[r*128 + tid];
    red[tid] = s;
  }
  __syncthreads();
  if (tid < 64){
    float inv_n = 1.f/(float)n;
    float mu = red[tid]*inv_n;
    float var = red[64+tid]*inv_n - mu*mu;
    float a = gamma[tid]*rsqrtf(var + EPS_BN);
    sc[tid] = a;
    sh[tid] = beta[tid] - mu*a;
  }
  __syncthreads();
  int i = blockIdx.x*256 + tid;
  if (i >= n) return;
  float a0 = b[0], a1 = b[1];
  const float* gp = g_in + (size_t)i*64;
  #pragma unroll
  for (int k=0;k<64;k++){
    float v = fmaf(gp[k], sc[k], sh[k]);
    a0 = fmaf(v, w[k*2+0], a0);
    a1 = fmaf(v, w[k*2+1], a1);
  }
  out[i*2+0] = a0;
  out[i*2+1] = a1;
}

extern "C" void kernel_launch(void* const* d_in, const int* in_sizes, int n_in,
                              void* d_out, int out_size, void* d_ws, size_t ws_size,
                              hipStream_t stream){
  const float* x     = (const float*)d_in[0];
  const int*   ei    = (const int*)d_in[1];
  const float* W1    = (const float*)d_in[2];
  const float* b1    = (const float*)d_in[3];
  const float* Wr    = (const float*)d_in[4];
  const float* br    = (const float*)d_in[5];
  const float* gamma = (const float*)d_in[6];
  const float* beta  = (const float*)d_in[7];
  const float* lw    = (const float*)d_in[8];
  const float* lb    = (const float*)d_in[9];
  const int N = N_NODES, E = N_EDGES;
  const int* row = ei;
  const int* col = ei + E;

  char* ws = (char*)d_ws;
  size_t off = 0;
  auto alloc = [&](size_t bytes)->void*{
    void* p = ws + off; off = (off + bytes + 255) & ~(size_t)255; return p; };
  int*            deg   = (int*)   alloc((size_t)N*4);
  float*          dinv  = (float*) alloc((size_t)N*4);
  int*            offs  = (int*)   alloc((size_t)(N+1)*4);
  int*            cur   = (int*)   alloc((size_t)N*4);
  int*            bsums = (int*)   alloc(64*4);
  int*            ep    = (int*)   alloc((size_t)E*4);
  unsigned short* xs    = (unsigned short*)alloc((size_t)N*128*2);
  unsigned short* T1u   = (unsigned short*)alloc((size_t)N*128*2);
  unsigned short* T1s   = (unsigned short*)alloc((size_t)N*128*2);
  unsigned short* Uu    = (unsigned short*)alloc((size_t)N*128*2);
  unsigned short* hs    = (unsigned short*)alloc((size_t)N*64*2);
  float*          gbuf  = (float*) alloc((size_t)N*64*4);
  unsigned short* WTh   = (unsigned short*)alloc((size_t)135168*2);
  unsigned short* WTl   = (unsigned short*)alloc((size_t)135168*2);
  float*          stats = (float*) alloc((size_t)10*2048*4);
  float*          scsh  = (float*) alloc((size_t)10*128*4);

  hipMemsetAsync(deg, 0, (size_t)N*4, stream);
  hipMemsetAsync(stats, 0, (size_t)10*2048*4, stream);
  deg_count<<<(E+255)/256, 256, 0, stream>>>(row, deg, E);
  make_dinv<<<(N+255)/256, 256, 0, stream>>>(deg, dinv, N);
  int nb = (N+1023)/1024;
  scan_block<<<nb, 1024, 0, stream>>>(deg, offs, bsums, N);
  scan_bsums<<<1, 64, 0, stream>>>(bsums, nb);
  scan_fix<<<nb, 1024, 0, stream>>>(offs, cur, bsums, N, E);
  csr_fill<<<(E+255)/256, 256, 0, stream>>>(row, col, cur, ep, E);

  cast_xs<<<((N*16)+255)/256, 256, 0, stream>>>(x, dinv, (uint4*)xs, N);
  transpose_w_split<<<(135168+255)/256, 256, 0, stream>>>(W1, Wr, WTh, WTl);

  // ---- layer 1 (SEGF=128): A0 = x fp32 (identity affine) ----
  spmm_bf16<128,true ><<<(N+15)/16, 256, 0, stream>>>(offs, ep, dinv, xs, T1u, T1s, N);
  spmm_bf16<128,false><<<(N+15)/16, 256, 0, stream>>>(offs, ep, dinv, T1s, Uu, nullptr, N);
  gemm_mfma<128><<<(N+63)/64, 256, 0, stream>>>(x, nullptr, T1u, Uu, WTh, WTl,
      b1, gbuf, stats, N);

  // ---- layers 2..10 (SEGF=64): A0 = gbuf fp32 + BN inline ----
  for (int L=0; L<9; ++L){
    bn_scale<<<((N*8)+255)/256, 256, 0, stream>>>(gbuf, dinv, hs,
        stats + (size_t)L*2048, scsh + (size_t)L*128,
        gamma + (size_t)L*64, beta + (size_t)L*64, N);
    spmm_bf16<64,true ><<<(N+31)/32, 256, 0, stream>>>(offs, ep, dinv, hs, T1u, T1s, N);
    spmm_bf16<64,false><<<(N+31)/32, 256, 0, stream>>>(offs, ep, dinv, T1s, Uu, nullptr, N);
    gemm_mfma<64><<<(N+63)/64, 256, 0, stream>>>(gbuf, scsh + (size_t)L*128, T1u, Uu,
        WTh + 24576 + (size_t)L*12288, WTl + 24576 + (size_t)L*12288,
        br + (size_t)L*64, gbuf, stats + (size_t)(L+1)*2048, N);
  }

  final_linear_bn<<<(N+255)/256, 256, 0, stream>>>(gbuf, stats + (size_t)9*2048,
      gamma + (size_t)9*64, beta + (size_t)9*64, lw, lb, (float*)d_out, N);
}